// Round 1
// baseline (581.529 us; speedup 1.0000x reference)
//
#include <hip/hip_runtime.h>
#include <hip/hip_bf16.h>
#include <stdint.h>

#define B_ 4
#define S_ 4096
#define D_ 2048
#define M_ 512
#define E_ (D_ + M_)   // 2560 combined width
#define BS_ (B_ * S_)  // 16384 rows
#define CH_ 32         // scan chunks per sequence
#define CL_ 128        // chunk length (CH_*CL_ == S_)

typedef __attribute__((ext_vector_type(8))) short short8;
typedef __attribute__((ext_vector_type(4))) short short4e;
typedef __attribute__((ext_vector_type(4))) float float4e;

__device__ __forceinline__ unsigned short f2bf(float f) {
    unsigned int u = __float_as_uint(f);
    u = (u + 0x7fffu + ((u >> 16) & 1u)) >> 16;   // RNE
    return (unsigned short)u;
}

__device__ __forceinline__ float sigmoidf(float x) {
    return 1.0f / (1.0f + expf(-x));
}

// ---- async global -> LDS, 16B per lane -------------------------------------
__device__ __forceinline__ void load_lds16(const unsigned short* g, unsigned short* l) {
    __builtin_amdgcn_global_load_lds(
        (const __attribute__((address_space(1))) unsigned int*)g,
        (__attribute__((address_space(3))) unsigned int*)l,
        16, 0, 0);
}

// ---- fp32 -> bf16 conversion: x into comb[:, 0:2048] (row stride E_) -------
__global__ void conv_x_kernel(const float* __restrict__ x, unsigned short* __restrict__ comb) {
    int i = blockIdx.x * blockDim.x + threadIdx.x;
    const int n4 = BS_ * D_ / 4;
    const int stride = gridDim.x * blockDim.x;
    for (; i < n4; i += stride) {
        int flat = i << 2;                 // fits in int (33.5M)
        int row = flat >> 11;              // D_ = 2048
        int col = flat & (D_ - 1);
        float4 xv = ((const float4*)x)[i];
        short4e o = { (short)f2bf(xv.x), (short)f2bf(xv.y),
                      (short)f2bf(xv.z), (short)f2bf(xv.w) };
        *(short4e*)(comb + (size_t)row * E_ + col) = o;
    }
}

// ---- fp32 -> bf16, contiguous (weights) ------------------------------------
__global__ void conv_gen(const float* __restrict__ in, unsigned short* __restrict__ out, int n4) {
    int i = blockIdx.x * blockDim.x + threadIdx.x;
    const int stride = gridDim.x * blockDim.x;
    for (; i < n4; i += stride) {
        float4 xv = ((const float4*)in)[i];
        short4e o = { (short)f2bf(xv.x), (short)f2bf(xv.y),
                      (short)f2bf(xv.z), (short)f2bf(xv.w) };
        ((short4e*)out)[i] = o;
    }
}

// ---- bf16 GEMM, B^T layout: C[m,n] = sum_k A[m,k]*B[n,k] (+bias, +x) -------
// 128x128 block tile, BK=64, 256 threads = 4 waves, each wave 64x64 (4x4 MFMA)
template<bool ADDX>
__global__ __launch_bounds__(256) void gemm_bt(
    const unsigned short* __restrict__ A, int lda,
    const unsigned short* __restrict__ Bm, int ldb,
    float* __restrict__ C, int ldc,
    const float* __restrict__ bias,
    const float* __restrict__ xres,
    int K)
{
    __shared__ unsigned short As[128 * 64];
    __shared__ unsigned short Bs[128 * 64];

    const int tid  = threadIdx.x;
    const int lane = tid & 63;
    const int wave = __builtin_amdgcn_readfirstlane(tid >> 6);
    const int bm0  = blockIdx.x * 128;
    const int bn0  = blockIdx.y * 128;
    const int wm   = wave & 1;   // wave row (0..1)
    const int wn   = wave >> 1;  // wave col (0..1)
    const int lm   = lane & 15;
    const int quad = lane >> 4;

    // Staging: 1024 granules (16B) per tile; thread handles granule i*256+tid.
    // LDS slot (r,c) holds global granule (r, c ^ (r&7))  -> xor swizzle.
    const unsigned short* ag[4];
    const unsigned short* bgp[4];
    unsigned short* al[4];
    unsigned short* bl[4];
#pragma unroll
    for (int i = 0; i < 4; ++i) {
        int g = i * 256 + tid;
        int r = g >> 3, c = g & 7;
        int cg = c ^ (r & 7);
        ag[i]  = A  + (size_t)(bm0 + r) * lda + cg * 8;
        bgp[i] = Bm + (size_t)(bn0 + r) * ldb + cg * 8;
        int lg = i * 256 + wave * 64;   // wave-uniform LDS granule base
        al[i] = As + lg * 8;
        bl[i] = Bs + lg * 8;
    }

    float4e acc[4][4];
    const float4e zero = {0.f, 0.f, 0.f, 0.f};
#pragma unroll
    for (int i = 0; i < 4; ++i)
#pragma unroll
        for (int j = 0; j < 4; ++j) acc[i][j] = zero;

    for (int k0 = 0; k0 < K; k0 += 64) {
#pragma unroll
        for (int i = 0; i < 4; ++i) {
            load_lds16(ag[i]  + k0, al[i]);
            load_lds16(bgp[i] + k0, bl[i]);
        }
        __syncthreads();
#pragma unroll
        for (int kk = 0; kk < 2; ++kk) {
            short8 af[4], bf[4];
#pragma unroll
            for (int i = 0; i < 4; ++i) {
                int ra = wm * 64 + i * 16 + lm;
                af[i] = *(const short8*)(As + ra * 64 + (((kk * 4 + quad) ^ (ra & 7)) * 8));
                int rb = wn * 64 + i * 16 + lm;
                bf[i] = *(const short8*)(Bs + rb * 64 + (((kk * 4 + quad) ^ (rb & 7)) * 8));
            }
#pragma unroll
            for (int i = 0; i < 4; ++i)
#pragma unroll
                for (int j = 0; j < 4; ++j)
                    acc[i][j] = __builtin_amdgcn_mfma_f32_16x16x32_bf16(af[i], bf[j], acc[i][j], 0, 0, 0);
        }
        __syncthreads();
    }

    // Epilogue: C/D layout col = lane&15, row = quad*4 + reg
#pragma unroll
    for (int i = 0; i < 4; ++i) {
#pragma unroll
        for (int j = 0; j < 4; ++j) {
            int row = bm0 + wm * 64 + i * 16 + quad * 4;
            int col = bn0 + wn * 64 + j * 16 + lm;
            float bb = bias[col];
#pragma unroll
            for (int r = 0; r < 4; ++r) {
                size_t idx = (size_t)(row + r) * ldc + col;
                float val = acc[i][j][r] + bb;
                if (ADDX) val += xres[idx];
                C[idx] = val;
            }
        }
    }
}

// ---- scan pass 1: per-chunk local end state (init 0) -----------------------
__global__ void scan_p1(const float* __restrict__ v, const float* __restrict__ tdp,
                        float* __restrict__ Ebuf) {
    int tid = blockIdx.x * blockDim.x + threadIdx.x;   // 0..B_*CH_*M_-1
    int m = tid & (M_ - 1);
    int c = (tid >> 9) & (CH_ - 1);
    int b = tid >> 14;
    float td = 0.9f * sigmoidf(tdp[m]) + 0.1f;
    const float* vp = v + (size_t)(b * S_ + c * CL_) * M_ + m;
    float s = 0.f;
#pragma unroll 4
    for (int t = 0; t < CL_; ++t) s = td * s + vp[(size_t)t * M_];
    Ebuf[(b * CH_ + c) * M_ + m] = s;
}

// ---- scan pass 2: sequential chunk combine (2048 threads) ------------------
__global__ void scan_p2(const float* __restrict__ tdp, const float* __restrict__ Ebuf,
                        float* __restrict__ Sbuf) {
    int tid = blockIdx.x * blockDim.x + threadIdx.x;   // 0..B_*M_-1
    int m = tid & (M_ - 1);
    int b = tid >> 9;
    float td = 0.9f * sigmoidf(tdp[m]) + 0.1f;
    float a = td;
#pragma unroll
    for (int i = 0; i < 7; ++i) a *= a;                // td^128
    float s = 0.f;
    for (int c = 0; c < CH_; ++c) {
        Sbuf[(b * CH_ + c) * M_ + m] = s;
        s = a * s + Ebuf[(b * CH_ + c) * M_ + m];
    }
}

// ---- scan pass 3: emit wv (bf16 into comb[:,2048:]) + final state ----------
__global__ void scan_p3(const float* __restrict__ v, const float* __restrict__ tdp,
                        const float* __restrict__ tfp, const float* __restrict__ ms,
                        const float* __restrict__ Sbuf, unsigned short* __restrict__ comb,
                        float* __restrict__ out_state) {
    int tid = blockIdx.x * blockDim.x + threadIdx.x;
    int m = tid & (M_ - 1);
    int c = (tid >> 9) & (CH_ - 1);
    int b = tid >> 14;
    float td  = 0.9f * sigmoidf(tdp[m]) + 0.1f;
    float add = ms[b * M_ + m] * sigmoidf(tfp[m]);
    float s   = Sbuf[(b * CH_ + c) * M_ + m];
    const float* vp = v + (size_t)(b * S_ + c * CL_) * M_ + m;
    unsigned short* cp = comb + (size_t)(b * S_ + c * CL_) * E_ + D_ + m;
    float w = 0.f;
#pragma unroll 4
    for (int t = 0; t < CL_; ++t) {
        s = td * s + vp[(size_t)t * M_];
        w = s + add;
        cp[(size_t)t * E_] = f2bf(w);
    }
    if (c == CH_ - 1) out_state[b * M_ + m] = w;
}

extern "C" void kernel_launch(void* const* d_in, const int* in_sizes, int n_in,
                              void* d_out, int out_size, void* d_ws, size_t ws_size,
                              hipStream_t stream) {
    const float* x    = (const float*)d_in[0];
    const float* ms   = (const float*)d_in[1];
    // d_in[2]=Wk, d_in[3]=bk are dead code in the reference
    const float* Wv   = (const float*)d_in[4];
    const float* bv   = (const float*)d_in[5];
    const float* Wg   = (const float*)d_in[6];
    const float* bg   = (const float*)d_in[7];
    const float* tdec = (const float*)d_in[8];
    const float* tfir = (const float*)d_in[9];

    float* out       = (float*)d_out;
    float* out_state = out + (size_t)BS_ * D_;

    char* ws = (char*)d_ws;
    size_t off = 0;
    unsigned short* comb = (unsigned short*)(ws + off); off += (size_t)BS_ * E_ * 2;  // 84 MB
    float*          vbuf = (float*)(ws + off);          off += (size_t)BS_ * M_ * 4;  // 33.5 MB
    unsigned short* Wvb  = (unsigned short*)(ws + off); off += (size_t)M_ * D_ * 2;   // 2 MB
    unsigned short* Wgb  = (unsigned short*)(ws + off); off += (size_t)D_ * E_ * 2;   // 10.5 MB
    float*          Ebuf = (float*)(ws + off);          off += (size_t)B_ * CH_ * M_ * 4;
    float*          Sbuf = (float*)(ws + off);          off += (size_t)B_ * CH_ * M_ * 4;

    // 1. conversions
    conv_x_kernel<<<4096, 256, 0, stream>>>(x, comb);
    conv_gen<<<512, 256, 0, stream>>>(Wv, Wvb, M_ * D_ / 4);
    conv_gen<<<2048, 256, 0, stream>>>(Wg, Wgb, D_ * E_ / 4);

    // 2. v = x @ Wv^T + bv   (fp32 out)
    gemm_bt<false><<<dim3(BS_ / 128, M_ / 128), 256, 0, stream>>>(
        comb, E_, Wvb, D_, vbuf, M_, bv, nullptr, D_);

    // 3. chunk-parallel scan -> wv bf16 into comb[:,2048:] + next_memory_state
    scan_p1<<<(B_ * CH_ * M_) / 256, 256, 0, stream>>>(vbuf, tdec, Ebuf);
    scan_p2<<<(B_ * M_) / 256, 256, 0, stream>>>(tdec, Ebuf, Sbuf);
    scan_p3<<<(B_ * CH_ * M_) / 256, 256, 0, stream>>>(vbuf, tdec, tfir, ms, Sbuf, comb, out_state);

    // 4. out = x + combined @ Wg^T + bg
    gemm_bt<true><<<dim3(BS_ / 128, D_ / 128), 256, 0, stream>>>(
        comb, E_, Wgb, E_, out, D_, bg, x, E_);
}

// Round 2
// 573.211 us; speedup vs baseline: 1.0145x; 1.0145x over previous
//
#include <hip/hip_runtime.h>
#include <hip/hip_bf16.h>
#include <stdint.h>

#define B_ 4
#define S_ 4096
#define D_ 2048
#define M_ 512
#define E_ (D_ + M_)   // 2560 combined width
#define BS_ (B_ * S_)  // 16384 rows
#define CH_ 32         // scan chunks per sequence
#define CL_ 128        // chunk length (CH_*CL_ == S_)

typedef __attribute__((ext_vector_type(8))) short short8;
typedef __attribute__((ext_vector_type(4))) short short4e;
typedef __attribute__((ext_vector_type(4))) float float4e;

__device__ __forceinline__ unsigned short f2bf(float f) {
    unsigned int u = __float_as_uint(f);
    u = (u + 0x7fffu + ((u >> 16) & 1u)) >> 16;   // RNE
    return (unsigned short)u;
}
__device__ __forceinline__ float bf2f(unsigned short h) {
    return __uint_as_float(((unsigned int)h) << 16);
}
__device__ __forceinline__ float sigmoidf(float x) {
    return 1.0f / (1.0f + expf(-x));
}

// ---- async global -> LDS, 16B per lane -------------------------------------
__device__ __forceinline__ void load_lds16(const unsigned short* g, unsigned short* l) {
    __builtin_amdgcn_global_load_lds(
        (const __attribute__((address_space(1))) unsigned int*)g,
        (__attribute__((address_space(3))) unsigned int*)l,
        16, 0, 0);
}

// ---- fp32 -> bf16 conversion: x into comb[:, 0:2048] (row stride E_) -------
__global__ void conv_x_kernel(const float* __restrict__ x, unsigned short* __restrict__ comb) {
    int i = blockIdx.x * blockDim.x + threadIdx.x;
    const int n4 = BS_ * D_ / 4;
    const int stride = gridDim.x * blockDim.x;
    for (; i < n4; i += stride) {
        int flat = i << 2;
        int row = flat >> 11;              // D_ = 2048
        int col = flat & (D_ - 1);
        float4 xv = ((const float4*)x)[i];
        short4e o = { (short)f2bf(xv.x), (short)f2bf(xv.y),
                      (short)f2bf(xv.z), (short)f2bf(xv.w) };
        *(short4e*)(comb + (size_t)row * E_ + col) = o;
    }
}

// ---- fp32 -> bf16 for both weight matrices in one launch -------------------
__global__ void conv_w_kernel(const float* __restrict__ Wv, unsigned short* __restrict__ Wvb,
                              const float* __restrict__ Wg, unsigned short* __restrict__ Wgb) {
    const int nv4 = M_ * D_ / 4;
    const int ng4 = D_ * E_ / 4;
    int i = blockIdx.x * blockDim.x + threadIdx.x;
    const int stride = gridDim.x * blockDim.x;
    for (; i < nv4 + ng4; i += stride) {
        const float* in;
        unsigned short* out;
        int j;
        if (i < nv4) { in = Wv; out = Wvb; j = i; }
        else         { in = Wg; out = Wgb; j = i - nv4; }
        float4 xv = ((const float4*)in)[j];
        short4e o = { (short)f2bf(xv.x), (short)f2bf(xv.y),
                      (short)f2bf(xv.z), (short)f2bf(xv.w) };
        ((short4e*)out)[j] = o;
    }
}

// ---- bf16 GEMM, B^T layout: C[m,n] = sum_k A[m,k]*B[n,k] (+bias, +resid) ---
// BMxBN block tile, BK=64, 256 threads = 4 waves (2x2), wave tile BM/2 x BN/2
template<int BM, int BN, bool ADDX, bool OUT_BF16>
__global__ __launch_bounds__(256) void gemm_bt(
    const unsigned short* __restrict__ A, int lda,
    const unsigned short* __restrict__ Bm, int ldb,
    void* __restrict__ Cv, int ldc,
    const float* __restrict__ bias,
    const unsigned short* __restrict__ resid, int resid_ld,
    int K)
{
    constexpr int MI = BM / 32;          // acc tiles per wave, M dir
    constexpr int NJ = BN / 32;          // acc tiles per wave, N dir
    constexpr int NGA = BM / 32;         // staging granule-iters for A (BM*8/256)
    constexpr int NGB = BN / 32;         // staging granule-iters for B

    __shared__ unsigned short As[BM * 64];
    __shared__ unsigned short Bs[BN * 64];

    const int tid  = threadIdx.x;
    const int lane = tid & 63;
    const int wave = __builtin_amdgcn_readfirstlane(tid >> 6);
    const int bn0  = blockIdx.x * BN;    // N tiles fastest -> A row-tile L2 reuse
    const int bm0  = blockIdx.y * BM;
    const int wm   = wave & 1;
    const int wn   = wave >> 1;
    const int lm   = lane & 15;
    const int quad = lane >> 4;

    // Staging: granule g -> LDS slot (r,c) holds global granule (r, c^(r&7))
    const unsigned short* ag[NGA];
    unsigned short* al[NGA];
#pragma unroll
    for (int i = 0; i < NGA; ++i) {
        int g = i * 256 + tid;
        int r = g >> 3, c = g & 7;
        int cg = c ^ (r & 7);
        ag[i] = A + (size_t)(bm0 + r) * lda + cg * 8;
        al[i] = As + (i * 256 + wave * 64) * 8;
    }
    const unsigned short* bgp[NGB];
    unsigned short* bl[NGB];
#pragma unroll
    for (int i = 0; i < NGB; ++i) {
        int g = i * 256 + tid;
        int r = g >> 3, c = g & 7;
        int cg = c ^ (r & 7);
        bgp[i] = Bm + (size_t)(bn0 + r) * ldb + cg * 8;
        bl[i] = Bs + (i * 256 + wave * 64) * 8;
    }

    float4e acc[MI][NJ];
    const float4e zero = {0.f, 0.f, 0.f, 0.f};
#pragma unroll
    for (int i = 0; i < MI; ++i)
#pragma unroll
        for (int j = 0; j < NJ; ++j) acc[i][j] = zero;

    for (int k0 = 0; k0 < K; k0 += 64) {
#pragma unroll
        for (int i = 0; i < NGA; ++i) load_lds16(ag[i] + k0, al[i]);
#pragma unroll
        for (int i = 0; i < NGB; ++i) load_lds16(bgp[i] + k0, bl[i]);
        __syncthreads();
#pragma unroll
        for (int kk = 0; kk < 2; ++kk) {
            short8 af[MI], bf[NJ];
#pragma unroll
            for (int i = 0; i < MI; ++i) {
                int ra = wm * (BM / 2) + i * 16 + lm;
                af[i] = *(const short8*)(As + ra * 64 + (((kk * 4 + quad) ^ (ra & 7)) * 8));
            }
#pragma unroll
            for (int j = 0; j < NJ; ++j) {
                int rb = wn * (BN / 2) + j * 16 + lm;
                bf[j] = *(const short8*)(Bs + rb * 64 + (((kk * 4 + quad) ^ (rb & 7)) * 8));
            }
#pragma unroll
            for (int i = 0; i < MI; ++i)
#pragma unroll
                for (int j = 0; j < NJ; ++j)
                    acc[i][j] = __builtin_amdgcn_mfma_f32_16x16x32_bf16(af[i], bf[j], acc[i][j], 0, 0, 0);
        }
        __syncthreads();
    }

    // Epilogue: C/D layout col = lane&15, row = quad*4 + reg
#pragma unroll
    for (int i = 0; i < MI; ++i) {
#pragma unroll
        for (int j = 0; j < NJ; ++j) {
            int row = bm0 + wm * (BM / 2) + i * 16 + quad * 4;
            int col = bn0 + wn * (BN / 2) + j * 16 + lm;
            float bb = bias[col];
#pragma unroll
            for (int r = 0; r < 4; ++r) {
                size_t idx = (size_t)(row + r) * ldc + col;
                float val = acc[i][j][r] + bb;
                if (ADDX) val += bf2f(resid[(size_t)(row + r) * resid_ld + col]);
                if (OUT_BF16) ((unsigned short*)Cv)[idx] = f2bf(val);
                else          ((float*)Cv)[idx] = val;
            }
        }
    }
}

// ---- scan pass 1: per-chunk local end state (init 0), bf16 v ---------------
__global__ void scan_p1(const unsigned short* __restrict__ v, const float* __restrict__ tdp,
                        float* __restrict__ Ebuf) {
    int tid = blockIdx.x * blockDim.x + threadIdx.x;   // 0..B_*CH_*M_-1
    int m = tid & (M_ - 1);
    int c = (tid >> 9) & (CH_ - 1);
    int b = tid >> 14;
    float td = 0.9f * sigmoidf(tdp[m]) + 0.1f;
    const unsigned short* vp = v + (size_t)(b * S_ + c * CL_) * M_ + m;
    float s = 0.f;
#pragma unroll 4
    for (int t = 0; t < CL_; ++t) s = td * s + bf2f(vp[(size_t)t * M_]);
    Ebuf[(b * CH_ + c) * M_ + m] = s;
}

// ---- scan pass 2 (prefix inlined) + emit wv bf16 + final state -------------
__global__ void scan_p3(const unsigned short* __restrict__ v, const float* __restrict__ tdp,
                        const float* __restrict__ tfp, const float* __restrict__ ms,
                        const float* __restrict__ Ebuf, unsigned short* __restrict__ comb,
                        float* __restrict__ out_state) {
    int tid = blockIdx.x * blockDim.x + threadIdx.x;
    int m = tid & (M_ - 1);
    int c = (tid >> 9) & (CH_ - 1);
    int b = tid >> 14;
    float td  = 0.9f * sigmoidf(tdp[m]) + 0.1f;
    float a = td;
#pragma unroll
    for (int i = 0; i < 7; ++i) a *= a;                // td^128
    // prefix: state entering chunk c
    float s = 0.f;
    for (int cp = 0; cp < c; ++cp)
        s = a * s + Ebuf[(b * CH_ + cp) * M_ + m];
    float add = ms[b * M_ + m] * sigmoidf(tfp[m]);
    const unsigned short* vp = v + (size_t)(b * S_ + c * CL_) * M_ + m;
    unsigned short* cp_ = comb + (size_t)(b * S_ + c * CL_) * E_ + D_ + m;
    float w = 0.f;
#pragma unroll 4
    for (int t = 0; t < CL_; ++t) {
        s = td * s + bf2f(vp[(size_t)t * M_]);
        w = s + add;
        cp_[(size_t)t * E_] = f2bf(w);
    }
    if (c == CH_ - 1) out_state[b * M_ + m] = w;
}

extern "C" void kernel_launch(void* const* d_in, const int* in_sizes, int n_in,
                              void* d_out, int out_size, void* d_ws, size_t ws_size,
                              hipStream_t stream) {
    const float* x    = (const float*)d_in[0];
    const float* ms   = (const float*)d_in[1];
    // d_in[2]=Wk, d_in[3]=bk are dead code in the reference
    const float* Wv   = (const float*)d_in[4];
    const float* bv   = (const float*)d_in[5];
    const float* Wg   = (const float*)d_in[6];
    const float* bg   = (const float*)d_in[7];
    const float* tdec = (const float*)d_in[8];
    const float* tfir = (const float*)d_in[9];

    float* out       = (float*)d_out;
    float* out_state = out + (size_t)BS_ * D_;

    char* ws = (char*)d_ws;
    size_t off = 0;
    unsigned short* comb = (unsigned short*)(ws + off); off += (size_t)BS_ * E_ * 2;  // 84 MB
    unsigned short* vbuf = (unsigned short*)(ws + off); off += (size_t)BS_ * M_ * 2;  // 16.8 MB
    unsigned short* Wvb  = (unsigned short*)(ws + off); off += (size_t)M_ * D_ * 2;   // 2 MB
    unsigned short* Wgb  = (unsigned short*)(ws + off); off += (size_t)D_ * E_ * 2;   // 10.5 MB
    float*          Ebuf = (float*)(ws + off);          off += (size_t)B_ * CH_ * M_ * 4;

    // 1. conversions
    conv_x_kernel<<<4096, 256, 0, stream>>>(x, comb);
    conv_w_kernel<<<1536, 256, 0, stream>>>(Wv, Wvb, Wg, Wgb);

    // 2. v = x @ Wv^T + bv  (bf16 out), 128x64 tiles -> 1024 blocks
    gemm_bt<128, 64, false, true><<<dim3(M_ / 64, BS_ / 128), 256, 0, stream>>>(
        comb, E_, Wvb, D_, vbuf, M_, bv, nullptr, 0, D_);

    // 3. chunk-parallel scan -> wv bf16 into comb[:,2048:] + next_memory_state
    scan_p1<<<(B_ * CH_ * M_) / 256, 256, 0, stream>>>(vbuf, tdec, Ebuf);
    scan_p3<<<(B_ * CH_ * M_) / 256, 256, 0, stream>>>(vbuf, tdec, tfir, ms, Ebuf, comb, out_state);

    // 4. out = x + combined @ Wg^T + bg   (residual from bf16 comb, L2/L3-hot)
    gemm_bt<128, 128, true, false><<<dim3(D_ / 128, BS_ / 128), 256, 0, stream>>>(
        comb, E_, Wgb, E_, out, D_, bg, comb, E_, E_);
}

// Round 3
// 541.512 us; speedup vs baseline: 1.0739x; 1.0585x over previous
//
#include <hip/hip_runtime.h>
#include <hip/hip_bf16.h>
#include <stdint.h>

#define B_ 4
#define S_ 4096
#define D_ 2048
#define M_ 512
#define E_ (D_ + M_)   // 2560 combined width
#define BS_ (B_ * S_)  // 16384 rows
#define CH_ 32         // scan chunks per sequence
#define CL_ 128        // chunk length (CH_*CL_ == S_)

typedef __attribute__((ext_vector_type(8))) short short8;
typedef __attribute__((ext_vector_type(4))) short short4e;
typedef __attribute__((ext_vector_type(4))) float float4e;

__device__ __forceinline__ unsigned short f2bf(float f) {
    unsigned int u = __float_as_uint(f);
    u = (u + 0x7fffu + ((u >> 16) & 1u)) >> 16;   // RNE
    return (unsigned short)u;
}
__device__ __forceinline__ float bf2f(unsigned short h) {
    return __uint_as_float(((unsigned int)h) << 16);
}
__device__ __forceinline__ float sigmoidf(float x) {
    return 1.0f / (1.0f + expf(-x));
}

// ---- async global -> LDS, 16B per lane -------------------------------------
__device__ __forceinline__ void load_lds16(const unsigned short* g, unsigned short* l) {
    __builtin_amdgcn_global_load_lds(
        (const __attribute__((address_space(1))) unsigned int*)g,
        (__attribute__((address_space(3))) unsigned int*)l,
        16, 0, 0);
}

// ---- fp32 -> bf16 conversion: x into comb[:, 0:2048] (row stride E_) -------
__global__ void conv_x_kernel(const float* __restrict__ x, unsigned short* __restrict__ comb) {
    int i = blockIdx.x * blockDim.x + threadIdx.x;
    const int n4 = BS_ * D_ / 4;
    const int stride = gridDim.x * blockDim.x;
    for (; i < n4; i += stride) {
        int flat = i << 2;
        int row = flat >> 11;              // D_ = 2048
        int col = flat & (D_ - 1);
        float4 xv = ((const float4*)x)[i];
        short4e o = { (short)f2bf(xv.x), (short)f2bf(xv.y),
                      (short)f2bf(xv.z), (short)f2bf(xv.w) };
        *(short4e*)(comb + (size_t)row * E_ + col) = o;
    }
}

// ---- fp32 -> bf16 for both weight matrices in one launch -------------------
__global__ void conv_w_kernel(const float* __restrict__ Wv, unsigned short* __restrict__ Wvb,
                              const float* __restrict__ Wg, unsigned short* __restrict__ Wgb) {
    const int nv4 = M_ * D_ / 4;
    const int ng4 = D_ * E_ / 4;
    int i = blockIdx.x * blockDim.x + threadIdx.x;
    const int stride = gridDim.x * blockDim.x;
    for (; i < nv4 + ng4; i += stride) {
        const float* in;
        unsigned short* out;
        int j;
        if (i < nv4) { in = Wv; out = Wvb; j = i; }
        else         { in = Wg; out = Wgb; j = i - nv4; }
        float4 xv = ((const float4*)in)[j];
        short4e o = { (short)f2bf(xv.x), (short)f2bf(xv.y),
                      (short)f2bf(xv.z), (short)f2bf(xv.w) };
        ((short4e*)out)[j] = o;
    }
}

// ---- bf16 GEMM, B^T layout: C[m,n] = sum_k A[m,k]*B[n,k] (+bias, +resid) ---
// BMxBN block tile, BK=64, 256 threads = 4 waves (2x2), wave tile BM/2 x BN/2
// Grid: blockIdx.x = row tile (fastest) -> consecutive blocks share B col-strip
template<int BM, int BN, bool ADDX, bool OUT_BF16>
__global__ __launch_bounds__(256) void gemm_bt(
    const unsigned short* __restrict__ A, int lda,
    const unsigned short* __restrict__ Bm, int ldb,
    void* __restrict__ Cv, int ldc,
    const float* __restrict__ bias,
    const unsigned short* __restrict__ resid, int resid_ld,
    int K)
{
    constexpr int MI = BM / 32;          // acc tiles per wave, M dir
    constexpr int NJ = BN / 32;          // acc tiles per wave, N dir
    constexpr int NGA = BM / 32;         // staging granule-iters for A
    constexpr int NGB = BN / 32;         // staging granule-iters for B

    __shared__ unsigned short As[BM * 64];
    __shared__ unsigned short Bs[BN * 64];

    const int tid  = threadIdx.x;
    const int lane = tid & 63;
    const int wave = __builtin_amdgcn_readfirstlane(tid >> 6);
    const int bm0  = blockIdx.x * BM;    // rows fastest
    const int bn0  = blockIdx.y * BN;
    const int wm   = wave & 1;
    const int wn   = wave >> 1;
    const int lm   = lane & 15;
    const int quad = lane >> 4;

    // Staging: granule g -> LDS slot (r,c) holds global granule (r, c^(r&7))
    const unsigned short* ag[NGA];
    unsigned short* al[NGA];
#pragma unroll
    for (int i = 0; i < NGA; ++i) {
        int g = i * 256 + tid;
        int r = g >> 3, c = g & 7;
        int cg = c ^ (r & 7);
        ag[i] = A + (size_t)(bm0 + r) * lda + cg * 8;
        al[i] = As + (i * 256 + wave * 64) * 8;
    }
    const unsigned short* bgp[NGB];
    unsigned short* bl[NGB];
#pragma unroll
    for (int i = 0; i < NGB; ++i) {
        int g = i * 256 + tid;
        int r = g >> 3, c = g & 7;
        int cg = c ^ (r & 7);
        bgp[i] = Bm + (size_t)(bn0 + r) * ldb + cg * 8;
        bl[i] = Bs + (i * 256 + wave * 64) * 8;
    }

    float4e acc[MI][NJ];
    const float4e zero = {0.f, 0.f, 0.f, 0.f};
#pragma unroll
    for (int i = 0; i < MI; ++i)
#pragma unroll
        for (int j = 0; j < NJ; ++j) acc[i][j] = zero;

    for (int k0 = 0; k0 < K; k0 += 64) {
#pragma unroll
        for (int i = 0; i < NGA; ++i) load_lds16(ag[i] + k0, al[i]);
#pragma unroll
        for (int i = 0; i < NGB; ++i) load_lds16(bgp[i] + k0, bl[i]);
        __syncthreads();
#pragma unroll
        for (int kk = 0; kk < 2; ++kk) {
            short8 af[MI], bf[NJ];
#pragma unroll
            for (int i = 0; i < MI; ++i) {
                int ra = wm * (BM / 2) + i * 16 + lm;
                af[i] = *(const short8*)(As + ra * 64 + (((kk * 4 + quad) ^ (ra & 7)) * 8));
            }
#pragma unroll
            for (int j = 0; j < NJ; ++j) {
                int rb = wn * (BN / 2) + j * 16 + lm;
                bf[j] = *(const short8*)(Bs + rb * 64 + (((kk * 4 + quad) ^ (rb & 7)) * 8));
            }
#pragma unroll
            for (int i = 0; i < MI; ++i)
#pragma unroll
                for (int j = 0; j < NJ; ++j)
                    acc[i][j] = __builtin_amdgcn_mfma_f32_16x16x32_bf16(af[i], bf[j], acc[i][j], 0, 0, 0);
        }
        __syncthreads();
    }

    // Epilogue: C/D layout col = lane&15, row = quad*4 + reg
#pragma unroll
    for (int i = 0; i < MI; ++i) {
#pragma unroll
        for (int j = 0; j < NJ; ++j) {
            int row = bm0 + wm * (BM / 2) + i * 16 + quad * 4;
            int col = bn0 + wn * (BN / 2) + j * 16 + lm;
            float bb = bias[col];
#pragma unroll
            for (int r = 0; r < 4; ++r) {
                size_t idx = (size_t)(row + r) * ldc + col;
                float val = acc[i][j][r] + bb;
                if (ADDX) val += bf2f(resid[(size_t)(row + r) * resid_ld + col]);
                if (OUT_BF16) ((unsigned short*)Cv)[idx] = f2bf(val);
                else          ((float*)Cv)[idx] = val;
            }
        }
    }
}

// ---- scan pass 1: per-chunk local end state (init 0), bf16 v ---------------
__global__ void scan_p1(const unsigned short* __restrict__ v, const float* __restrict__ tdp,
                        float* __restrict__ Ebuf) {
    int tid = blockIdx.x * blockDim.x + threadIdx.x;   // 0..B_*CH_*M_-1
    int m = tid & (M_ - 1);
    int c = (tid >> 9) & (CH_ - 1);
    int b = tid >> 14;
    float td = 0.9f * sigmoidf(tdp[m]) + 0.1f;
    const unsigned short* vp = v + (size_t)(b * S_ + c * CL_) * M_ + m;
    float s = 0.f;
#pragma unroll 4
    for (int t = 0; t < CL_; ++t) s = td * s + bf2f(vp[(size_t)t * M_]);
    Ebuf[(b * CH_ + c) * M_ + m] = s;
}

// ---- scan pass 2 (prefix inlined) + emit wv bf16 + final state -------------
__global__ void scan_p3(const unsigned short* __restrict__ v, const float* __restrict__ tdp,
                        const float* __restrict__ tfp, const float* __restrict__ ms,
                        const float* __restrict__ Ebuf, unsigned short* __restrict__ comb,
                        float* __restrict__ out_state) {
    int tid = blockIdx.x * blockDim.x + threadIdx.x;
    int m = tid & (M_ - 1);
    int c = (tid >> 9) & (CH_ - 1);
    int b = tid >> 14;
    float td  = 0.9f * sigmoidf(tdp[m]) + 0.1f;
    float a = td;
#pragma unroll
    for (int i = 0; i < 7; ++i) a *= a;                // td^128
    // prefix: state entering chunk c
    float s = 0.f;
    for (int cp = 0; cp < c; ++cp)
        s = a * s + Ebuf[(b * CH_ + cp) * M_ + m];
    float add = ms[b * M_ + m] * sigmoidf(tfp[m]);
    const unsigned short* vp = v + (size_t)(b * S_ + c * CL_) * M_ + m;
    unsigned short* cp_ = comb + (size_t)(b * S_ + c * CL_) * E_ + D_ + m;
    float w = 0.f;
#pragma unroll 4
    for (int t = 0; t < CL_; ++t) {
        s = td * s + bf2f(vp[(size_t)t * M_]);
        w = s + add;
        cp_[(size_t)t * E_] = f2bf(w);
    }
    if (c == CH_ - 1) out_state[b * M_ + m] = w;
}

extern "C" void kernel_launch(void* const* d_in, const int* in_sizes, int n_in,
                              void* d_out, int out_size, void* d_ws, size_t ws_size,
                              hipStream_t stream) {
    const float* x    = (const float*)d_in[0];
    const float* ms   = (const float*)d_in[1];
    // d_in[2]=Wk, d_in[3]=bk are dead code in the reference
    const float* Wv   = (const float*)d_in[4];
    const float* bv   = (const float*)d_in[5];
    const float* Wg   = (const float*)d_in[6];
    const float* bg   = (const float*)d_in[7];
    const float* tdec = (const float*)d_in[8];
    const float* tfir = (const float*)d_in[9];

    float* out       = (float*)d_out;
    float* out_state = out + (size_t)BS_ * D_;

    char* ws = (char*)d_ws;
    size_t off = 0;
    unsigned short* comb = (unsigned short*)(ws + off); off += (size_t)BS_ * E_ * 2;  // 84 MB
    unsigned short* vbuf = (unsigned short*)(ws + off); off += (size_t)BS_ * M_ * 2;  // 16.8 MB
    unsigned short* Wvb  = (unsigned short*)(ws + off); off += (size_t)M_ * D_ * 2;   // 2 MB
    unsigned short* Wgb  = (unsigned short*)(ws + off); off += (size_t)D_ * E_ * 2;   // 10.5 MB
    float*          Ebuf = (float*)(ws + off);          off += (size_t)B_ * CH_ * M_ * 4;

    // 1. conversions
    conv_x_kernel<<<4096, 256, 0, stream>>>(x, comb);
    conv_w_kernel<<<1536, 256, 0, stream>>>(Wv, Wvb, Wg, Wgb);

    // 2. v = x @ Wv^T + bv  (bf16 out); BM=64,BN=256: comb streamed only 2x
    gemm_bt<64, 256, false, true><<<dim3(BS_ / 64, M_ / 256), 256, 0, stream>>>(
        comb, E_, Wvb, D_, vbuf, M_, bv, nullptr, 0, D_);

    // 3. chunk-parallel scan -> wv bf16 into comb[:,2048:] + next_memory_state
    scan_p1<<<(B_ * CH_ * M_) / 256, 256, 0, stream>>>(vbuf, tdec, Ebuf);
    scan_p3<<<(B_ * CH_ * M_) / 256, 256, 0, stream>>>(vbuf, tdec, tfir, ms, Ebuf, comb, out_state);

    // 4. out = x + combined @ Wg^T + bg  (rows-fastest grid, bf16 resid)
    gemm_bt<128, 128, true, false><<<dim3(BS_ / 128, D_ / 128), 256, 0, stream>>>(
        comb, E_, Wgb, E_, out, D_, bg, comb, E_, E_);
}